// Round 1
// baseline (754.899 us; speedup 1.0000x reference)
//
#include <hip/hip_runtime.h>
#include <hip/hip_bf16.h>
#include <stdint.h>

typedef unsigned short ushort_t;
typedef __bf16 bf16x8 __attribute__((ext_vector_type(8)));
typedef float    f32x4 __attribute__((ext_vector_type(4)));
typedef unsigned short us4 __attribute__((ext_vector_type(4)));

#define QK_SCALE 0.12751744f   /* log2(e) / sqrt(128) : folded into Q so softmax uses exp2 */
#define NEG_BIG  -1e30f

__device__ __forceinline__ unsigned short f2bf(float f) {
    union { float f; unsigned int u; } v; v.f = f;
    unsigned int u = v.u;
    return (unsigned short)((u + 0x7FFFu + ((u >> 16) & 1u)) >> 16);  // RNE
}

// async global->LDS, 16B per lane. LDS dest is wave-uniform base + lane*16.
__device__ __forceinline__ void gload16(const void* g, void* l) {
    __builtin_amdgcn_global_load_lds(
        (__attribute__((address_space(1))) void*)(uintptr_t)g,
        (__attribute__((address_space(3))) void*)(uint32_t)(uintptr_t)l,
        16, 0, 0);
}

// ---------------- prep kernels ----------------

__global__ __launch_bounds__(256) void cvt_bf16_kernel(
    const float4* __restrict__ in, us4* __restrict__ out, int n4) {
    int i = blockIdx.x * 256 + threadIdx.x;
    if (i >= n4) return;
    float4 v = in[i];
    us4 o; o[0] = f2bf(v.x); o[1] = f2bf(v.y); o[2] = f2bf(v.z); o[3] = f2bf(v.w);
    out[i] = o;
}

// in [R][C] fp32  ->  out [C][R] bf16   (64x64 LDS tile transpose)
__global__ __launch_bounds__(256) void transpose_bf16(
    const float* __restrict__ in, ushort_t* __restrict__ out, int R, int C) {
    __shared__ float t[64][65];
    int c0 = blockIdx.x * 64, r0 = blockIdx.y * 64;
    int cc = threadIdx.x & 63, rr = threadIdx.x >> 6;
#pragma unroll
    for (int i = 0; i < 16; ++i) {
        int r = i * 4 + rr;
        t[r][cc] = in[(size_t)(r0 + r) * C + c0 + cc];
    }
    __syncthreads();
#pragma unroll
    for (int i = 0; i < 16; ++i) {
        int r = i * 4 + rr;
        out[(size_t)(c0 + r) * R + r0 + cc] = f2bf(t[cc][r]);
    }
}

// rope table: [L][64] of (cos, sin)
__global__ __launch_bounds__(256) void rope_table_kernel(float2* __restrict__ rope) {
    int i = blockIdx.x * 256 + threadIdx.x;     // L*64 = 131072 exactly
    int l = i >> 6, j = i & 63;
    float inv = exp2f((float)j * -0.20762050593046f);  // 10000^(-j/64)
    float f = (float)l * inv;
    rope[i] = make_float2(cosf(f), sinf(f));
}

// ---------------- GEMM:  C[M][N] = A[M][K] * Bt[N][K]^T  (bf16 in, fp32 acc) ----------------
// 128x128 tile, BK=64, 256 threads (4 waves), global_load_lds w/ pre-swizzled source,
// XOR-swizzled ds_read_b128 ((row&7)<<4), 2-barrier K loop.
// EPI 0: plain fp32 C write.   EPI 1: qkv epilogue (rope on q/k, transpose on v).

template <int EPI>
__global__ __launch_bounds__(256, 2)
void gemm_bt(const ushort_t* __restrict__ A, const ushort_t* __restrict__ Bt,
             int M, int N, int K,
             float* __restrict__ C,
             ushort_t* __restrict__ Qb, ushort_t* __restrict__ Kb,
             ushort_t* __restrict__ Vt, const float2* __restrict__ rope) {
    constexpr int MI = (EPI == 1) ? 2 : 4;
    constexpr int NI = (EPI == 1) ? 8 : 4;

    __shared__ __attribute__((aligned(16))) ushort_t ldsA[128 * 64];
    __shared__ __attribute__((aligned(16))) ushort_t ldsB[128 * 64];
    char* ldsAc = (char*)ldsA;
    char* ldsBc = (char*)ldsB;

    const int tid  = threadIdx.x;
    const int lane = tid & 63, wid = tid >> 6;
    const int lr = lane & 15, lg = lane >> 4;

    const int nbn = N >> 7;
    const int nwg = gridDim.x;
    const int bid = blockIdx.x;
    const int wg  = (bid & 7) * (nwg >> 3) + (bid >> 3);   // XCD-contiguous chunks
    const int bm  = wg / nbn, bn = wg % nbn;

    const int arow0 = (EPI == 1) ? wid * 32 : (wid >> 1) * 64;
    const int bcol0 = (EPI == 1) ? 0        : (wid & 1) * 64;

    // staging: chunk r covers rows [r*32, r*32+32); lane's 16B block, source pre-swizzled
    const int colb = ((tid & 7) << 4) ^ (((tid >> 3) & 7) << 4);
    const int rowi = tid >> 3;                       // 0..31
    const char* Ap = (const char*)A + ((size_t)(bm * 128 + rowi) * K) * 2 + colb;
    const char* Bp = (const char*)Bt + ((size_t)(bn * 128 + rowi) * K) * 2 + colb;
    const size_t rstr = (size_t)32 * K * 2;
    char* ldA = ldsAc + wid * 1024;
    char* ldB = ldsBc + wid * 1024;

    f32x4 acc[MI][NI];
#pragma unroll
    for (int i = 0; i < MI; ++i)
#pragma unroll
        for (int j = 0; j < NI; ++j) acc[i][j] = (f32x4){0.f, 0.f, 0.f, 0.f};

    for (int k0 = 0; k0 < K; k0 += 64) {
#pragma unroll
        for (int r = 0; r < 4; ++r) {
            gload16(Ap + r * rstr + (size_t)k0 * 2, ldA + r * 4096);
            gload16(Bp + r * rstr + (size_t)k0 * 2, ldB + r * 4096);
        }
        __syncthreads();
#pragma unroll
        for (int kk = 0; kk < 2; ++kk) {
            bf16x8 af[MI], bfv[NI];
#pragma unroll
            for (int mi = 0; mi < MI; ++mi) {
                int row = arow0 + mi * 16 + lr;
                int off = (row << 7) + kk * 64 + lg * 16;
                off ^= (row & 7) << 4;
                af[mi] = *(const bf16x8*)(ldsAc + off);
            }
#pragma unroll
            for (int ni = 0; ni < NI; ++ni) {
                int row = bcol0 + ni * 16 + lr;
                int off = (row << 7) + kk * 64 + lg * 16;
                off ^= (row & 7) << 4;
                bfv[ni] = *(const bf16x8*)(ldsBc + off);
            }
#pragma unroll
            for (int mi = 0; mi < MI; ++mi)
#pragma unroll
                for (int ni = 0; ni < NI; ++ni)
                    acc[mi][ni] = __builtin_amdgcn_mfma_f32_16x16x32_bf16(
                        af[mi], bfv[ni], acc[mi][ni], 0, 0, 0);
        }
        __syncthreads();
    }

    if constexpr (EPI == 0) {
#pragma unroll
        for (int mi = 0; mi < MI; ++mi) {
            int gr0 = bm * 128 + arow0 + mi * 16 + lg * 4;
#pragma unroll
            for (int ni = 0; ni < NI; ++ni) {
                int gc = bn * 128 + bcol0 + ni * 16 + lr;
#pragma unroll
                for (int r = 0; r < 4; ++r)
                    C[(size_t)(gr0 + r) * N + gc] = acc[mi][ni][r];
            }
        }
    } else {
        // one block column == one (which, head): N layout is [3][H=16][D=128]
        const int which = bn >> 4, h = bn & 15;
#pragma unroll
        for (int mi = 0; mi < MI; ++mi) {
            int gr0 = bm * 128 + arow0 + mi * 16 + lg * 4;   // = b*L + l0 (4 consecutive l)
            int b = gr0 >> 11, l0 = gr0 & 2047;
            if (which == 2) {                                 // V -> [BH][D][L] (transposed)
#pragma unroll
                for (int ni = 0; ni < NI; ++ni) {
                    int d = ni * 16 + lr;
                    us4 pk;
#pragma unroll
                    for (int r = 0; r < 4; ++r) pk[r] = f2bf(acc[mi][ni][r]);
                    *(us4*)(Vt + ((size_t)(b * 16 + h) * 128 + d) * 2048 + l0) = pk;
                }
            } else {                                          // Q/K: rope, -> [BH][L][D]
                ushort_t* dst = (which == 0) ? Qb : Kb;
                const float sc = (which == 0) ? QK_SCALE : 1.0f;
#pragma unroll
                for (int ni = 0; ni < 4; ++ni) {
                    int j = ni * 16 + lr;                     // d < 64 ; pair at d+64 = frag ni+4
#pragma unroll
                    for (int r = 0; r < 4; ++r) {
                        float2 cs = rope[(size_t)(l0 + r) * 64 + j];
                        float x1 = acc[mi][ni][r], x2 = acc[mi][ni + 4][r];
                        size_t base = ((size_t)(b * 16 + h) * 2048 + (l0 + r)) * 128;
                        dst[base + j]      = f2bf((x1 * cs.x - x2 * cs.y) * sc);
                        dst[base + j + 64] = f2bf((x2 * cs.x + x1 * cs.y) * sc);
                    }
                }
            }
        }
    }
}

// ---------------- causal flash attention ----------------
// Q,K: [BH][L][128] bf16 (Q pre-scaled by log2e/sqrt(D)); V: [BH][128][L] bf16
// out AO: [B][L][H*128] bf16. 4 independent waves/block, 32 q-rows/wave, KBLK=64.

__global__ __launch_bounds__(256, 2)
void attn_fwd(const ushort_t* __restrict__ Qb, const ushort_t* __restrict__ Kb,
              const ushort_t* __restrict__ Vt, ushort_t* __restrict__ AO) {
    constexpr int L = 2048;
    __shared__ __attribute__((aligned(16))) ushort_t P_lds[4][32 * 64];

    const int tid  = threadIdx.x;
    const int lane = tid & 63, wid = tid >> 6;
    const int lr = lane & 15, lg = lane >> 4;

    // grid remap: each XCD (bid&7) owns 8 consecutive heads -> K/V stay L2-resident
    const int bid  = blockIdx.x;
    const int slot = bid >> 3;
    const int head = (bid & 7) * 8 + (slot >> 4);
    const int qt   = slot & 15;
    const int q0w  = qt * 128 + wid * 32;

    const ushort_t* Qh = Qb + (size_t)head * L * 128;
    const ushort_t* Kh = Kb + (size_t)head * L * 128;
    const ushort_t* Vh = Vt + (size_t)head * 128 * L;
    char* Pw = (char*)&P_lds[wid][0];

    // Q fragments hoisted to registers
    bf16x8 qa[2][4];
#pragma unroll
    for (int mi = 0; mi < 2; ++mi)
#pragma unroll
        for (int kk = 0; kk < 4; ++kk)
            qa[mi][kk] = *(const bf16x8*)(Qh + (size_t)(q0w + mi * 16 + lr) * 128 + kk * 32 + lg * 8);

    f32x4 o[2][8];
    float m_[2][4], l_[2][4];
#pragma unroll
    for (int mi = 0; mi < 2; ++mi) {
#pragma unroll
        for (int ni = 0; ni < 8; ++ni) o[mi][ni] = (f32x4){0.f, 0.f, 0.f, 0.f};
#pragma unroll
        for (int r = 0; r < 4; ++r) { m_[mi][r] = -__builtin_inff(); l_[mi][r] = 0.f; }
    }

    const int ntile = ((q0w + 31) >> 6) + 1;
    for (int t = 0; t < ntile; ++t) {
        const int k0 = t << 6;
        f32x4 s[2][4];
#pragma unroll
        for (int mi = 0; mi < 2; ++mi)
#pragma unroll
            for (int ni = 0; ni < 4; ++ni) s[mi][ni] = (f32x4){0.f, 0.f, 0.f, 0.f};

        // S = Q K^T  (K fragments straight from global; L2-resident)
#pragma unroll
        for (int kk = 0; kk < 4; ++kk) {
            bf16x8 kf[4];
#pragma unroll
            for (int ni = 0; ni < 4; ++ni)
                kf[ni] = *(const bf16x8*)(Kh + (size_t)(k0 + ni * 16 + lr) * 128 + kk * 32 + lg * 8);
#pragma unroll
            for (int mi = 0; mi < 2; ++mi)
#pragma unroll
                for (int ni = 0; ni < 4; ++ni)
                    s[mi][ni] = __builtin_amdgcn_mfma_f32_16x16x32_bf16(qa[mi][kk], kf[ni], s[mi][ni], 0, 0, 0);
        }

        if (k0 + 63 > q0w) {   // diagonal tile: causal mask
#pragma unroll
            for (int mi = 0; mi < 2; ++mi)
#pragma unroll
                for (int ni = 0; ni < 4; ++ni)
#pragma unroll
                    for (int r = 0; r < 4; ++r) {
                        int qg = q0w + mi * 16 + lg * 4 + r;
                        int kg = k0 + ni * 16 + lr;
                        s[mi][ni][r] = (kg > qg) ? NEG_BIG : s[mi][ni][r];
                    }
        }

        float alpha[2][4];
#pragma unroll
        for (int mi = 0; mi < 2; ++mi) {
            float t4[4];
#pragma unroll
            for (int r = 0; r < 4; ++r)
                t4[r] = fmaxf(fmaxf(s[mi][0][r], s[mi][1][r]), fmaxf(s[mi][2][r], s[mi][3][r]));
#pragma unroll
            for (int msk = 1; msk <= 8; msk <<= 1)
#pragma unroll
                for (int r = 0; r < 4; ++r) t4[r] = fmaxf(t4[r], __shfl_xor(t4[r], msk, 64));
#pragma unroll
            for (int r = 0; r < 4; ++r) {
                float mn = fmaxf(m_[mi][r], t4[r]);
                alpha[mi][r] = exp2f(m_[mi][r] - mn);
                m_[mi][r] = mn;
            }
            float rs[4] = {0.f, 0.f, 0.f, 0.f};
#pragma unroll
            for (int ni = 0; ni < 4; ++ni)
#pragma unroll
                for (int r = 0; r < 4; ++r) {
                    float p = exp2f(s[mi][ni][r] - m_[mi][r]);
                    rs[r] += p;
                    int row32 = mi * 16 + lg * 4 + r;
                    int off = (row32 << 7) + ((ni * 16 + lr) << 1);
                    off ^= (row32 & 7) << 4;
                    *(ushort_t*)(Pw + off) = f2bf(p);
                }
#pragma unroll
            for (int msk = 1; msk <= 8; msk <<= 1)
#pragma unroll
                for (int r = 0; r < 4; ++r) rs[r] += __shfl_xor(rs[r], msk, 64);
#pragma unroll
            for (int r = 0; r < 4; ++r) l_[mi][r] = l_[mi][r] * alpha[mi][r] + rs[r];
        }

        // rescale O
#pragma unroll
        for (int mi = 0; mi < 2; ++mi)
#pragma unroll
            for (int ni = 0; ni < 8; ++ni)
#pragma unroll
                for (int r = 0; r < 4; ++r) o[mi][ni][r] *= alpha[mi][r];

        asm volatile("s_waitcnt lgkmcnt(0)" ::: "memory");
        __builtin_amdgcn_sched_barrier(0);

        // P (A-layout, swizzled) ; V fragments from global V^T ; O += P V
        bf16x8 pa[2][2];
#pragma unroll
        for (int mi2 = 0; mi2 < 2; ++mi2)
#pragma unroll
            for (int kk = 0; kk < 2; ++kk) {
                int row = mi2 * 16 + lr;
                int off = (row << 7) + kk * 64 + lg * 16;
                off ^= (row & 7) << 4;
                pa[mi2][kk] = *(const bf16x8*)(Pw + off);
            }
#pragma unroll
        for (int ni = 0; ni < 8; ++ni)
#pragma unroll
            for (int kk = 0; kk < 2; ++kk) {
                bf16x8 vf = *(const bf16x8*)(Vh + (size_t)(ni * 16 + lr) * L + k0 + kk * 32 + lg * 8);
#pragma unroll
                for (int mi2 = 0; mi2 < 2; ++mi2)
                    o[mi2][ni] = __builtin_amdgcn_mfma_f32_16x16x32_bf16(pa[mi2][kk], vf, o[mi2][ni], 0, 0, 0);
            }
    }

    // epilogue: normalize and store [B][L][H*128]
    const int b = head >> 4, h = head & 15;
#pragma unroll
    for (int mi = 0; mi < 2; ++mi) {
        float inv[4];
#pragma unroll
        for (int r = 0; r < 4; ++r) inv[r] = 1.f / l_[mi][r];
#pragma unroll
        for (int ni = 0; ni < 8; ++ni)
#pragma unroll
            for (int r = 0; r < 4; ++r) {
                size_t off = ((size_t)(b * 2048 + q0w + mi * 16 + lg * 4 + r)) * 2048 + h * 128 + ni * 16 + lr;
                AO[off] = f2bf(o[mi][ni][r] * inv[r]);
            }
    }
}

// ---------------- launcher ----------------

extern "C" void kernel_launch(void* const* d_in, const int* in_sizes, int n_in,
                              void* d_out, int out_size, void* d_ws, size_t ws_size,
                              hipStream_t stream) {
    const float* x    = (const float*)d_in[0];   // [4,2048,2048]
    const float* Wqkv = (const float*)d_in[1];   // [2048,6144]
    const float* Wo   = (const float*)d_in[2];   // [2048,2048]
    float* out = (float*)d_out;                  // [4,2048,2048] fp32

    char* w = (char*)d_ws;
    ushort_t* xb   = (ushort_t*)(w);               // x bf16             33,554,432 B
    ushort_t* W1t  = (ushort_t*)(w + 33554432);    // Wqkv^T bf16        25,165,824 B
    ushort_t* Wot  = (ushort_t*)(w + 58720256);    // Wo^T bf16           8,388,608 B
    ushort_t* Qb   = (ushort_t*)(w + 67108864);    // Q roped [BH][L][D] 33,554,432 B
    ushort_t* Kbf  = (ushort_t*)(w + 100663296);   // K roped [BH][L][D] 33,554,432 B
    ushort_t* Vt   = (ushort_t*)(w + 134217728);   // V^T    [BH][D][L]  33,554,432 B
    ushort_t* AO   = (ushort_t*)(w + 167772160);   // attn out bf16      33,554,432 B
    float2*   rope = (float2*)(w + 201326592);     // [L][64] cos/sin     1,048,576 B
                                                   // total ~202.4 MB

    cvt_bf16_kernel<<<16384, 256, 0, stream>>>((const float4*)x, (us4*)xb, 4194304);
    transpose_bf16<<<dim3(96, 32), 256, 0, stream>>>(Wqkv, W1t, 2048, 6144);
    transpose_bf16<<<dim3(32, 32), 256, 0, stream>>>(Wo, Wot, 2048, 2048);
    rope_table_kernel<<<512, 256, 0, stream>>>(rope);

    // qkv GEMM + fused rope/reshape epilogue
    gemm_bt<1><<<3072, 256, 0, stream>>>(xb, W1t, 8192, 6144, 2048,
                                         nullptr, Qb, Kbf, Vt, rope);
    // causal flash attention
    attn_fwd<<<1024, 256, 0, stream>>>(Qb, Kbf, Vt, AO);
    // output projection
    gemm_bt<0><<<1024, 256, 0, stream>>>(AO, Wot, 8192, 2048, 2048,
                                         out, nullptr, nullptr, nullptr, nullptr);
}